// Round 3
// baseline (304.115 us; speedup 1.0000x reference)
//
#include <hip/hip_runtime.h>
#include <hip/hip_fp16.h>
#include <stdint.h>

// Problem constants (hardcoded per reference)
#define NROWS 131072   // B*L
#define DIM   256      // D
#define HDK   128      // H*DK
#define BM    16       // rows per workgroup

typedef _Float16 f16x8 __attribute__((ext_vector_type(8)));
typedef float    f32x4 __attribute__((ext_vector_type(4)));

// ---------------------------------------------------------------------------
// Pack W_q, W_k, W_v (256x128) and W_o (128x256) into fragment-linear fp16.
// Proj p at p*32768: frag idx = ((nt*8 + ks)*64 + lane)*8 + j,
//   value = W[ks*32 + (lane>>4)*8 + j][nt*16 + (lane&15)]   (head-major tiles)
// W_o at 98304: frag idx = ((nto*4 + ks)*64 + lane)*8 + j, with COLUMN PERMUTE:
//   actual col n = (nto>>2)*64 + (lane&15)*4 + (nto&3)
// so that the wave's 4 C-tiles give each lane 4 CONSECUTIVE output columns
// (final gate becomes float4 loads/stores with no cross-lane shuffle).
// ---------------------------------------------------------------------------
__global__ void pack_w(const float* __restrict__ Wq, const float* __restrict__ Wk,
                       const float* __restrict__ Wv, const float* __restrict__ Wo,
                       _Float16* __restrict__ wt) {
  int t = blockIdx.x * 256 + threadIdx.x;   // 0 .. 131071
  int seg = t >> 15;                        // 0..3
  int i = t & 32767;
  int j = i & 7;
  int l = (i >> 3) & 63;
  int rest = i >> 9;                        // nt*KS + ks
  const float* W;
  int N, k, n;
  if (seg < 3) {
    W = (seg == 0) ? Wq : ((seg == 1) ? Wk : Wv);
    N = HDK;
    int ks = rest & 7, nt = rest >> 3;
    k = ks * 32 + ((l >> 4) << 3) + j;      // 0..255
    n = nt * 16 + (l & 15);                 // 0..127
  } else {
    W = Wo;
    N = DIM;
    int ks = rest & 3, nt = rest >> 2;      // nt = nto in 0..15
    k = ks * 32 + ((l >> 4) << 3) + j;      // 0..127
    n = ((nt >> 2) << 6) + ((l & 15) << 2) + (nt & 3);  // permuted column
  }
  wt[t] = (_Float16)W[k * N + n];
}

// ---------------------------------------------------------------------------
// Fused main kernel v3:
//  - NO LDS staging of Q/K/V: each wave loads its MFMA A-fragments directly
//    from global f32 (redundant across the 4 waves; L1/L2-served), converts
//    to fp16 in-register. One barrier total (sVAf).
//  - per-head gated softmax in-register (16-lane groups)
//  - V_att fragment-linear in 4 KB LDS (conflict-free)
//  - W_o column-permuted packing -> final SiLU gate is pure float4 I/O
//  LDS = 4 KB, VGPR capped for 8 waves/SIMD -> ~100% occupancy target.
// ---------------------------------------------------------------------------
__launch_bounds__(256, 8)
__global__ void uan_main(const float* __restrict__ Qg, const float* __restrict__ Kg,
                         const float* __restrict__ Vg, const _Float16* __restrict__ wt,
                         const float* __restrict__ Wl, const float* __restrict__ blv,
                         const float* __restrict__ Wsv, const float* __restrict__ bsv,
                         float* __restrict__ outg) {
  __shared__ __align__(16) _Float16 sVAf[256 * 8];   // 4096 B: V_att A-fragments

  const int tid  = threadIdx.x;
  const int lane = tid & 63;
  const int wave = tid >> 6;        // 0..3
  const int c16  = lane & 15;       // col within 16-tile / head-dim index
  const int kg   = lane >> 4;       // k-group 0..3
  const size_t row0 = (size_t)blockIdx.x * BM;

  // ---- projections: Qh,Kh,Vh via mfma_f32_16x16x32_f16, A direct from global ----
  // A-frag (16x16x32): lane holds row (lane&15), k = ks*32 + kg*8 + j
  // wave w owns heads {2w, 2w+1}
  f32x4 accP[3][2] = {};
#pragma unroll
  for (int p = 0; p < 3; ++p) {
    const float* Xp = (p == 0) ? Qg : ((p == 1) ? Kg : Vg);
    const float* abase = Xp + (row0 + c16) * DIM + kg * 8;
#pragma unroll
    for (int ks = 0; ks < 8; ++ks) {
      float4 a0 = *(const float4*)(abase + ks * 32);
      float4 a1 = *(const float4*)(abase + ks * 32 + 4);
      f16x8 af;
      af[0] = (_Float16)a0.x; af[1] = (_Float16)a0.y;
      af[2] = (_Float16)a0.z; af[3] = (_Float16)a0.w;
      af[4] = (_Float16)a1.x; af[5] = (_Float16)a1.y;
      af[6] = (_Float16)a1.z; af[7] = (_Float16)a1.w;
#pragma unroll
      for (int nt = 0; nt < 2; ++nt) {
        const f16x8 bf = *(const f16x8*)(wt + p * 32768 +
                          (size_t)(((wave * 2 + nt) * 8 + ks) * 64 + lane) * 8);
        accP[p][nt] = __builtin_amdgcn_mfma_f32_16x16x32_f16(af, bf, accP[p][nt], 0, 0, 0);
      }
    }
  }

  // ---- per-head gated softmax, in-register ----
  // C-fragment: value q of tile nt is row (kg*4+q), col c16 of head (wave*2+nt).
  const float wl0 = Wl[c16], wl1 = Wl[16 + c16], wsc = Wsv[c16];
  const float bl0 = blv[0], bl1 = blv[1], bs0 = bsv[0];

#pragma unroll
  for (int nt = 0; nt < 2; ++nt) {
#pragma unroll
    for (int q = 0; q < 4; ++q) {
      float qh = accP[0][nt][q];
      float kh = accP[1][nt][q];
      float vh = accP[2][nt][q];
      float left  = kh * qh;
      float right = vh * qh;
      float d0 = left * wl0;
      float d1 = left * wl1;
#pragma unroll
      for (int m = 1; m < 16; m <<= 1) {
        d0 += __shfl_xor(d0, m, 16);
        d1 += __shfl_xor(d1, m, 16);
      }
      float m0 = 1.0f / (1.0f + __expf(-(d0 + bl0)));
      float m1 = 1.0f / (1.0f + __expf(-(d1 + bl1)));
      float fix = left * m0 * m1;          // |fix| <~ 36 -> exp safe without max-sub
      float e   = __expf(fix);
      float num = e * wsc;
      float den = e;
#pragma unroll
      for (int m = 1; m < 16; m <<= 1) {
        num += __shfl_xor(num, m, 16);
        den += __shfl_xor(den, m, 16);
      }
      float score = num / den + bs0;
      float va = score * right;
      // fragment-linear store: col = wave*32 + nt*16 + c16 -> ks'=wave,
      // kg' = nt*2 + (c16>>3), j = c16&7, lane' = kg'*16 + (kg*4+q)
      sVAf[(size_t)((wave * 64) + (nt * 2 + (c16 >> 3)) * 16 + kg * 4 + q) * 8 + (c16 & 7)]
          = (_Float16)va;
    }
  }
  __syncthreads();

  // ---- W_o GEMM: (BM x 128) @ (128 x 256); wave w owns out cols [64w, 64w+64)
  //      (column-permuted: C-tile nt holds cols  w*64 + c16*4 + nt) ----
  f32x4 accO[4] = {};
#pragma unroll
  for (int ks = 0; ks < 4; ++ks) {
    const f16x8 af = *(const f16x8*)(sVAf + (size_t)(ks * 64 + lane) * 8);
#pragma unroll
    for (int nt = 0; nt < 4; ++nt) {
      const int nto = wave * 4 + nt;
      const f16x8 bf = *(const f16x8*)(wt + 98304 +
                        (size_t)((nto * 4 + ks) * 64 + lane) * 8);
      accO[nt] = __builtin_amdgcn_mfma_f32_16x16x32_f16(af, bf, accO[nt], 0, 0, 0);
    }
  }

  // ---- final: out = silu((V*Q) * V_att_out) -- float4 loads/stores ----
  // lane (kg,c16), q: row = kg*4+q, cols = wave*64 + c16*4 + {0..3} = accO[0..3][q]
#pragma unroll
  for (int q = 0; q < 4; ++q) {
    const int row = kg * 4 + q;
    const size_t gb = (row0 + row) * DIM + wave * 64 + c16 * 4;
    float4 v4 = *(const float4*)(Vg + gb);
    float4 q4 = *(const float4*)(Qg + gb);
    float4 o;
    {
      float att = v4.x * q4.x * accO[0][q]; o.x = att / (1.0f + __expf(-att));
      att = v4.y * q4.y * accO[1][q];       o.y = att / (1.0f + __expf(-att));
      att = v4.z * q4.z * accO[2][q];       o.z = att / (1.0f + __expf(-att));
      att = v4.w * q4.w * accO[3][q];       o.w = att / (1.0f + __expf(-att));
    }
    *(float4*)(outg + gb) = o;
  }
}

// ---------------------------------------------------------------------------
extern "C" void kernel_launch(void* const* d_in, const int* in_sizes, int n_in,
                              void* d_out, int out_size, void* d_ws, size_t ws_size,
                              hipStream_t stream) {
  const float* Q  = (const float*)d_in[0];
  const float* K  = (const float*)d_in[1];
  const float* V  = (const float*)d_in[2];
  const float* Wq = (const float*)d_in[3];
  const float* Wk = (const float*)d_in[4];
  const float* Wv = (const float*)d_in[5];
  const float* Wo = (const float*)d_in[6];
  const float* Wl = (const float*)d_in[7];
  const float* bl = (const float*)d_in[8];
  const float* Ws = (const float*)d_in[9];
  const float* bs = (const float*)d_in[10];
  _Float16* wt = (_Float16*)d_ws;   // 131072 halves = 256 KB of scratch
  float* out = (float*)d_out;

  pack_w<<<512, 256, 0, stream>>>(Wq, Wk, Wv, Wo, wt);
  uan_main<<<NROWS / BM, 256, 0, stream>>>(Q, K, V, wt, Wl, bl, Ws, bs, out);
}

// Round 4
// 303.406 us; speedup vs baseline: 1.0023x; 1.0023x over previous
//
#include <hip/hip_runtime.h>
#include <hip/hip_fp16.h>
#include <stdint.h>

// Problem constants (hardcoded per reference)
#define NROWS 131072   // B*L
#define DIM   256      // D
#define HDK   128      // H*DK
#define BM    16       // rows per workgroup

typedef _Float16 f16x8 __attribute__((ext_vector_type(8)));
typedef float    f32x4 __attribute__((ext_vector_type(4)));

// ---------------------------------------------------------------------------
// Pack W_q, W_k, W_v (256x128) and W_o (128x256) into fragment-linear fp16.
// Proj p at p*32768: frag idx = ((nt*8 + ks)*64 + lane)*8 + j,
//   value = W[ks*32 + (lane>>4)*8 + j][nt*16 + (lane&15)]   (head-major tiles)
// W_o at 98304: frag idx = ((nto*4 + ks)*64 + lane)*8 + j, with COLUMN PERMUTE:
//   actual col n = (nto>>2)*64 + (lane&15)*4 + (nto&3)
// so the wave's 4 C-tiles give each lane 4 CONSECUTIVE output columns.
// ---------------------------------------------------------------------------
__global__ void pack_w(const float* __restrict__ Wq, const float* __restrict__ Wk,
                       const float* __restrict__ Wv, const float* __restrict__ Wo,
                       _Float16* __restrict__ wt) {
  int t = blockIdx.x * 256 + threadIdx.x;   // 0 .. 131071
  int seg = t >> 15;                        // 0..3
  int i = t & 32767;
  int j = i & 7;
  int l = (i >> 3) & 63;
  int rest = i >> 9;                        // nt*KS + ks
  const float* W;
  int N, k, n;
  if (seg < 3) {
    W = (seg == 0) ? Wq : ((seg == 1) ? Wk : Wv);
    N = HDK;
    int ks = rest & 7, nt = rest >> 3;
    k = ks * 32 + ((l >> 4) << 3) + j;      // 0..255
    n = nt * 16 + (l & 15);                 // 0..127
  } else {
    W = Wo;
    N = DIM;
    int ks = rest & 3, nt = rest >> 2;      // nt = nto in 0..15
    k = ks * 32 + ((l >> 4) << 3) + j;      // 0..127
    n = ((nt >> 2) << 6) + ((l & 15) << 2) + (nt & 3);  // permuted column
  }
  wt[t] = (_Float16)W[k * N + n];
}

// ---------------------------------------------------------------------------
// Fused main kernel v4: R3 structure, but each phase issues its loads as an
// explicit register batch (8 A + 8 B in flight per half-phase) so the wave
// has deep memory-level parallelism. VGPR budget relaxed to <=128 (4 w/SIMD).
// ---------------------------------------------------------------------------
__launch_bounds__(256, 4)
__global__ void uan_main(const float* __restrict__ Qg, const float* __restrict__ Kg,
                         const float* __restrict__ Vg, const _Float16* __restrict__ wt,
                         const float* __restrict__ Wl, const float* __restrict__ blv,
                         const float* __restrict__ Wsv, const float* __restrict__ bsv,
                         float* __restrict__ outg) {
  __shared__ __align__(16) _Float16 sVAf[256 * 8];   // 4096 B: V_att A-fragments

  const int tid  = threadIdx.x;
  const int lane = tid & 63;
  const int wave = tid >> 6;        // 0..3
  const int c16  = lane & 15;       // col within 16-tile / head-dim index
  const int kg   = lane >> 4;       // k-group 0..3
  const size_t row0 = (size_t)blockIdx.x * BM;

  // ---- projections: Qh,Kh,Vh via mfma_f32_16x16x32_f16, A direct from global ----
  // A-frag (16x16x32): lane holds row (lane&15), k = ks*32 + kg*8 + j
  // wave w owns heads {2w, 2w+1}
  f32x4 accP[3][2] = {};
#pragma unroll
  for (int p = 0; p < 3; ++p) {
    const float* Xp = (p == 0) ? Qg : ((p == 1) ? Kg : Vg);
    const float* abase = Xp + (row0 + c16) * DIM + kg * 8;
    const _Float16* wb = wt + p * 32768 + (size_t)(wave * 2 * 8 * 64 + lane) * 8;
#pragma unroll
    for (int h = 0; h < 2; ++h) {          // half-phase: ks = h*4 .. h*4+3
      float4 a0[4], a1[4];
      f16x8 bfr[4][2];
      // batch-issue all 16 loads of this half-phase
#pragma unroll
      for (int i = 0; i < 4; ++i) {
        const int ks = h * 4 + i;
        a0[i] = *(const float4*)(abase + ks * 32);
        a1[i] = *(const float4*)(abase + ks * 32 + 4);
        bfr[i][0] = *(const f16x8*)(wb + (size_t)(ks * 64) * 8);
        bfr[i][1] = *(const f16x8*)(wb + (size_t)((8 + ks) * 64) * 8);
      }
      // then consume
#pragma unroll
      for (int i = 0; i < 4; ++i) {
        f16x8 af;
        af[0] = (_Float16)a0[i].x; af[1] = (_Float16)a0[i].y;
        af[2] = (_Float16)a0[i].z; af[3] = (_Float16)a0[i].w;
        af[4] = (_Float16)a1[i].x; af[5] = (_Float16)a1[i].y;
        af[6] = (_Float16)a1[i].z; af[7] = (_Float16)a1[i].w;
        accP[p][0] = __builtin_amdgcn_mfma_f32_16x16x32_f16(af, bfr[i][0], accP[p][0], 0, 0, 0);
        accP[p][1] = __builtin_amdgcn_mfma_f32_16x16x32_f16(af, bfr[i][1], accP[p][1], 0, 0, 0);
      }
    }
  }

  // ---- per-head gated softmax, in-register ----
  // C-fragment: value q of tile nt is row (kg*4+q), col c16 of head (wave*2+nt).
  const float wl0 = Wl[c16], wl1 = Wl[16 + c16], wsc = Wsv[c16];
  const float bl0 = blv[0], bl1 = blv[1], bs0 = bsv[0];

#pragma unroll
  for (int nt = 0; nt < 2; ++nt) {
#pragma unroll
    for (int q = 0; q < 4; ++q) {
      float qh = accP[0][nt][q];
      float kh = accP[1][nt][q];
      float vh = accP[2][nt][q];
      float left  = kh * qh;
      float right = vh * qh;
      float d0 = left * wl0;
      float d1 = left * wl1;
#pragma unroll
      for (int m = 1; m < 16; m <<= 1) {
        d0 += __shfl_xor(d0, m, 16);
        d1 += __shfl_xor(d1, m, 16);
      }
      float m0 = 1.0f / (1.0f + __expf(-(d0 + bl0)));
      float m1 = 1.0f / (1.0f + __expf(-(d1 + bl1)));
      float fix = left * m0 * m1;          // |fix| <~ 36 -> exp safe without max-sub
      float e   = __expf(fix);
      float num = e * wsc;
      float den = e;
#pragma unroll
      for (int m = 1; m < 16; m <<= 1) {
        num += __shfl_xor(num, m, 16);
        den += __shfl_xor(den, m, 16);
      }
      float score = num / den + bs0;
      float va = score * right;
      // fragment-linear store: col = wave*32 + nt*16 + c16 -> ks'=wave,
      // kg' = nt*2 + (c16>>3), j = c16&7, lane' = kg'*16 + (kg*4+q)
      sVAf[(size_t)((wave * 64) + (nt * 2 + (c16 >> 3)) * 16 + kg * 4 + q) * 8 + (c16 & 7)]
          = (_Float16)va;
    }
  }
  __syncthreads();

  // ---- W_o GEMM: (BM x 128) @ (128 x 256); wave w owns out cols [64w, 64w+64)
  //      (column-permuted: C-tile nt holds cols  w*64 + c16*4 + nt) ----
  f32x4 accO[4] = {};
  {
    // batch-issue all 16 B-frag loads
    f16x8 bo[4][4];
    const _Float16* wob = wt + 98304 + (size_t)(wave * 4 * 4 * 64 + lane) * 8;
#pragma unroll
    for (int nt = 0; nt < 4; ++nt)
#pragma unroll
      for (int ks = 0; ks < 4; ++ks)
        bo[nt][ks] = *(const f16x8*)(wob + (size_t)((nt * 4 + ks) * 64) * 8);
#pragma unroll
    for (int ks = 0; ks < 4; ++ks) {
      const f16x8 af = *(const f16x8*)(sVAf + (size_t)(ks * 64 + lane) * 8);
#pragma unroll
      for (int nt = 0; nt < 4; ++nt)
        accO[nt] = __builtin_amdgcn_mfma_f32_16x16x32_f16(af, bo[nt][ks], accO[nt], 0, 0, 0);
    }
  }

  // ---- final: out = silu((V*Q) * V_att_out) -- float4 loads/stores ----
  // lane (kg,c16), q: row = kg*4+q, cols = wave*64 + c16*4 + {0..3} = accO[0..3][q]
  float4 v4[4], q4[4];
#pragma unroll
  for (int q = 0; q < 4; ++q) {
    const size_t gb = (row0 + kg * 4 + q) * DIM + wave * 64 + c16 * 4;
    v4[q] = *(const float4*)(Vg + gb);
    q4[q] = *(const float4*)(Qg + gb);
  }
#pragma unroll
  for (int q = 0; q < 4; ++q) {
    const size_t gb = (row0 + kg * 4 + q) * DIM + wave * 64 + c16 * 4;
    float4 o;
    float att = v4[q].x * q4[q].x * accO[0][q]; o.x = att / (1.0f + __expf(-att));
    att = v4[q].y * q4[q].y * accO[1][q];       o.y = att / (1.0f + __expf(-att));
    att = v4[q].z * q4[q].z * accO[2][q];       o.z = att / (1.0f + __expf(-att));
    att = v4[q].w * q4[q].w * accO[3][q];       o.w = att / (1.0f + __expf(-att));
    *(float4*)(outg + gb) = o;
  }
}

// ---------------------------------------------------------------------------
extern "C" void kernel_launch(void* const* d_in, const int* in_sizes, int n_in,
                              void* d_out, int out_size, void* d_ws, size_t ws_size,
                              hipStream_t stream) {
  const float* Q  = (const float*)d_in[0];
  const float* K  = (const float*)d_in[1];
  const float* V  = (const float*)d_in[2];
  const float* Wq = (const float*)d_in[3];
  const float* Wk = (const float*)d_in[4];
  const float* Wv = (const float*)d_in[5];
  const float* Wo = (const float*)d_in[6];
  const float* Wl = (const float*)d_in[7];
  const float* bl = (const float*)d_in[8];
  const float* Ws = (const float*)d_in[9];
  const float* bs = (const float*)d_in[10];
  _Float16* wt = (_Float16*)d_ws;   // 131072 halves = 256 KB of scratch
  float* out = (float*)d_out;

  pack_w<<<512, 256, 0, stream>>>(Wq, Wk, Wv, Wo, wt);
  uan_main<<<NROWS / BM, 256, 0, stream>>>(Q, K, V, wt, Wl, bl, Ws, bs, out);
}

// Round 5
// 189.536 us; speedup vs baseline: 1.6045x; 1.6008x over previous
//
#include <hip/hip_runtime.h>
#include <hip/hip_fp16.h>
#include <stdint.h>

// Problem constants (hardcoded per reference)
#define NROWS 131072   // B*L
#define DIM   256      // D
#define HDK   128      // H*DK
#define BM    16       // rows per tile
#define TPB   8        // tiles per block
#define NBLK  (NROWS / BM / TPB)   // 1024 blocks

typedef _Float16 f16x8 __attribute__((ext_vector_type(8)));
typedef float    f32x4 __attribute__((ext_vector_type(4)));

// ---------------------------------------------------------------------------
// Pack W_q, W_k, W_v (256x128) and W_o (128x256) into fragment-linear fp16.
// Proj p at p*32768: frag idx = ((nt*8 + ks)*64 + lane)*8 + j,
//   value = W[ks*32 + (lane>>4)*8 + j][nt*16 + (lane&15)]   (nt = head)
// W_o at 98304: frag idx = ((nto*4 + ks)*64 + lane)*8 + j, COLUMN PERMUTE:
//   actual col n = (nto>>1)*32 + (lane&15)*2 + (nto&1)
// so wave w (tiles nto=2w,2w+1) gives each lane 2 consecutive output columns.
// ---------------------------------------------------------------------------
__global__ void pack_w(const float* __restrict__ Wq, const float* __restrict__ Wk,
                       const float* __restrict__ Wv, const float* __restrict__ Wo,
                       _Float16* __restrict__ wt) {
  int t = blockIdx.x * 256 + threadIdx.x;   // 0 .. 131071
  int seg = t >> 15;                        // 0..3
  int i = t & 32767;
  int j = i & 7;
  int l = (i >> 3) & 63;
  int rest = i >> 9;                        // nt*KS + ks
  const float* W;
  int N, k, n;
  if (seg < 3) {
    W = (seg == 0) ? Wq : ((seg == 1) ? Wk : Wv);
    N = HDK;
    int ks = rest & 7, nt = rest >> 3;
    k = ks * 32 + ((l >> 4) << 3) + j;      // 0..255
    n = nt * 16 + (l & 15);                 // 0..127
  } else {
    W = Wo;
    N = DIM;
    int ks = rest & 3, nt = rest >> 2;      // nt = nto in 0..15
    k = ks * 32 + ((l >> 4) << 3) + j;      // 0..127
    n = ((nt >> 1) << 5) + ((l & 15) << 1) + (nt & 1);  // permuted column
  }
  wt[t] = (_Float16)W[k * N + n];
}

// ---------------------------------------------------------------------------
// v5: persistent-weight waves. 512 threads = 8 waves; wave w owns head w and
// W_o output cols [32w, 32w+32). All 32 B-fragments loaded ONCE to registers,
// then loop over 8 row-tiles: LDS-stage QKV (shared, no redundancy) -> proj
// MFMA -> in-register softmax -> sVAf -> W_o MFMA -> float2 SiLU finale.
// Weight L2 traffic drops 8x vs v4; A-fragment global redundancy eliminated.
// ---------------------------------------------------------------------------
__launch_bounds__(512, 2)
__global__ void uan_main(const float* __restrict__ Qg, const float* __restrict__ Kg,
                         const float* __restrict__ Vg, const _Float16* __restrict__ wt,
                         const float* __restrict__ Wl, const float* __restrict__ blv,
                         const float* __restrict__ Wsv, const float* __restrict__ bsv,
                         float* __restrict__ outg) {
  __shared__ __align__(16) _Float16 sF[1536 * 8];    // 24576 B: QKV A-fragments
  __shared__ __align__(16) _Float16 sVAf[256 * 8];   //  4096 B: V_att A-fragments

  const int tid  = threadIdx.x;
  const int lane = tid & 63;
  const int w    = tid >> 6;        // wave 0..7 == head
  const int c16  = lane & 15;
  const int kg   = lane >> 4;

  // ---- load held B-fragments (once per block life) ----
  f16x8 bwp[24];   // proj: [p*8 + ks], head w
#pragma unroll
  for (int p = 0; p < 3; ++p)
#pragma unroll
    for (int ks = 0; ks < 8; ++ks)
      bwp[p * 8 + ks] = *(const f16x8*)(wt + p * 32768 +
                         (size_t)(((w * 8 + ks) * 64) + lane) * 8);
  f16x8 bo[8];     // W_o: [nt*4 + ks], tiles nto = 2w, 2w+1
#pragma unroll
  for (int nt = 0; nt < 2; ++nt)
#pragma unroll
    for (int ks = 0; ks < 4; ++ks)
      bo[nt * 4 + ks] = *(const f16x8*)(wt + 98304 +
                         (size_t)((((2 * w + nt) * 4 + ks) * 64) + lane) * 8);

  const float wl0 = Wl[c16], wl1 = Wl[16 + c16], wsc = Wsv[c16];
  const float bl0 = blv[0], bl1 = blv[1], bs0 = bsv[0];

  for (int t = 0; t < TPB; ++t) {
    const size_t row0 = ((size_t)blockIdx.x * TPB + t) * BM;

    // ---- stage QKV tile as fp16 A-fragments (cooperative, no redundancy) ----
    // thread handles frags f = tid + {0,512,1024}: p = it, ks = tid>>6, ln = lane
    {
      const int ks = w;           // tid>>6
      const int ln = lane;
#pragma unroll
      for (int p = 0; p < 3; ++p) {
        const float* base = (p == 0) ? Qg : ((p == 1) ? Kg : Vg);
        const float* src = base + (row0 + (ln & 15)) * DIM + ks * 32 + ((ln >> 4) << 3);
        float4 a0 = *(const float4*)src;
        float4 a1 = *(const float4*)(src + 4);
        f16x8 h;
        h[0] = (_Float16)a0.x; h[1] = (_Float16)a0.y;
        h[2] = (_Float16)a0.z; h[3] = (_Float16)a0.w;
        h[4] = (_Float16)a1.x; h[5] = (_Float16)a1.y;
        h[6] = (_Float16)a1.z; h[7] = (_Float16)a1.w;
        *(f16x8*)(sF + (size_t)((p * 8 + ks) * 64 + ln) * 8) = h;
      }
    }
    __syncthreads();

    // ---- projections: head w, A from LDS, B held ----
    f32x4 accP[3] = {};
#pragma unroll
    for (int p = 0; p < 3; ++p)
#pragma unroll
      for (int ks = 0; ks < 8; ++ks) {
        const f16x8 af = *(const f16x8*)(sF + (size_t)(((p * 8 + ks) * 64) + lane) * 8);
        accP[p] = __builtin_amdgcn_mfma_f32_16x16x32_f16(af, bwp[p * 8 + ks], accP[p], 0, 0, 0);
      }

    // ---- gated softmax in-register; C-frag: value q = row kg*4+q, col c16 ----
#pragma unroll
    for (int q = 0; q < 4; ++q) {
      float qh = accP[0][q];
      float kh = accP[1][q];
      float vh = accP[2][q];
      float left  = kh * qh;
      float right = vh * qh;
      float d0 = left * wl0;
      float d1 = left * wl1;
#pragma unroll
      for (int m = 1; m < 16; m <<= 1) {
        d0 += __shfl_xor(d0, m, 16);
        d1 += __shfl_xor(d1, m, 16);
      }
      float m0 = 1.0f / (1.0f + __expf(-(d0 + bl0)));
      float m1 = 1.0f / (1.0f + __expf(-(d1 + bl1)));
      float fix = left * m0 * m1;          // |fix| <~ 40: exp safe in f32
      float e   = __expf(fix);
      float num = e * wsc;
      float den = e;
#pragma unroll
      for (int m = 1; m < 16; m <<= 1) {
        num += __shfl_xor(num, m, 16);
        den += __shfl_xor(den, m, 16);
      }
      float score = num / den + bs0;
      float va = score * right;
      // V_att col = w*16 + c16; frag-linear: ks' = w>>1, kg' = (w&1)*2 + (c16>>3)
      sVAf[(size_t)((w >> 1) * 64 + ((w & 1) * 2 + (c16 >> 3)) * 16 + kg * 4 + q) * 8
           + (c16 & 7)] = (_Float16)va;
    }
    __syncthreads();

    // ---- W_o: A = sVAf (LDS), B held; tiles nto = 2w, 2w+1 ----
    f32x4 accO[2] = {};
#pragma unroll
    for (int ks = 0; ks < 4; ++ks) {
      const f16x8 af = *(const f16x8*)(sVAf + (size_t)(ks * 64 + lane) * 8);
      accO[0] = __builtin_amdgcn_mfma_f32_16x16x32_f16(af, bo[ks],     accO[0], 0, 0, 0);
      accO[1] = __builtin_amdgcn_mfma_f32_16x16x32_f16(af, bo[4 + ks], accO[1], 0, 0, 0);
    }

    // ---- final: out = silu((V*Q) * V_att_out); lane cols = w*32 + c16*2 + {0,1} ----
#pragma unroll
    for (int q = 0; q < 4; ++q) {
      const size_t gb = (row0 + kg * 4 + q) * DIM + w * 32 + c16 * 2;
      float2 v2 = *(const float2*)(Vg + gb);
      float2 q2 = *(const float2*)(Qg + gb);
      float att0 = v2.x * q2.x * accO[0][q];
      float att1 = v2.y * q2.y * accO[1][q];
      float2 o;
      o.x = att0 / (1.0f + __expf(-att0));
      o.y = att1 / (1.0f + __expf(-att1));
      *(float2*)(outg + gb) = o;
    }
  }
}

// ---------------------------------------------------------------------------
extern "C" void kernel_launch(void* const* d_in, const int* in_sizes, int n_in,
                              void* d_out, int out_size, void* d_ws, size_t ws_size,
                              hipStream_t stream) {
  const float* Q  = (const float*)d_in[0];
  const float* K  = (const float*)d_in[1];
  const float* V  = (const float*)d_in[2];
  const float* Wq = (const float*)d_in[3];
  const float* Wk = (const float*)d_in[4];
  const float* Wv = (const float*)d_in[5];
  const float* Wo = (const float*)d_in[6];
  const float* Wl = (const float*)d_in[7];
  const float* bl = (const float*)d_in[8];
  const float* Ws = (const float*)d_in[9];
  const float* bs = (const float*)d_in[10];
  _Float16* wt = (_Float16*)d_ws;   // 131072 halves = 256 KB of scratch
  float* out = (float*)d_out;

  pack_w<<<512, 256, 0, stream>>>(Wq, Wk, Wv, Wo, wt);
  uan_main<<<NBLK, 512, 0, stream>>>(Q, K, V, wt, Wl, bl, Ws, bs, out);
}

// Round 6
// 146.912 us; speedup vs baseline: 2.0701x; 1.2901x over previous
//
#include <hip/hip_runtime.h>
#include <hip/hip_fp16.h>
#include <stdint.h>

// Problem constants (hardcoded per reference)
#define NROWS 131072   // B*L
#define DIM   256      // D
#define HDK   128      // H*DK
#define BM    16       // rows per tile
#define TPB   8        // tiles per block
#define NBLK  (NROWS / BM / TPB)   // 1024 blocks

typedef _Float16 f16x8 __attribute__((ext_vector_type(8)));
typedef float    f32x4 __attribute__((ext_vector_type(4)));

// ---------------------------------------------------------------------------
// Pack W_q, W_k, W_v (256x128) and W_o (128x256) into fragment-linear fp16.
// Proj p at p*32768: frag idx = ((nt*8 + ks)*64 + lane)*8 + j,
//   value = W[ks*32 + (lane>>4)*8 + j][nt*16 + (lane&15)]   (nt = head)
// W_o at 98304: frag idx = ((nto*4 + ks)*64 + lane)*8 + j, COLUMN PERMUTE:
//   actual col n = (nto>>1)*32 + (lane&15)*2 + (nto&1)
// so wave w (tiles nto=2w,2w+1) gives each lane 2 consecutive output columns.
// ---------------------------------------------------------------------------
__global__ void pack_w(const float* __restrict__ Wq, const float* __restrict__ Wk,
                       const float* __restrict__ Wv, const float* __restrict__ Wo,
                       _Float16* __restrict__ wt) {
  int t = blockIdx.x * 256 + threadIdx.x;   // 0 .. 131071
  int seg = t >> 15;                        // 0..3
  int i = t & 32767;
  int j = i & 7;
  int l = (i >> 3) & 63;
  int rest = i >> 9;                        // nt*KS + ks
  const float* W;
  int N, k, n;
  if (seg < 3) {
    W = (seg == 0) ? Wq : ((seg == 1) ? Wk : Wv);
    N = HDK;
    int ks = rest & 7, nt = rest >> 3;
    k = ks * 32 + ((l >> 4) << 3) + j;      // 0..255
    n = nt * 16 + (l & 15);                 // 0..127
  } else {
    W = Wo;
    N = DIM;
    int ks = rest & 3, nt = rest >> 2;      // nt = nto in 0..15
    k = ks * 32 + ((l >> 4) << 3) + j;      // 0..127
    n = ((nt >> 1) << 5) + ((l & 15) << 1) + (nt & 1);  // permuted column
  }
  wt[t] = (_Float16)W[k * N + n];
}

// ---------------------------------------------------------------------------
// v6: persistent-weight waves (R5) + two structural cuts:
//  (a) proj MFMA with SWAPPED operands -> lane holds P^T: row=c16, hd=kg*4+q.
//      Softmax 16-wide reductions = 3 register adds + 2 shuffles (64->8 shfl).
//  (b) double-buffered sF + software-pipelined staging: tile t+1's global
//      loads are issued before tile t's compute; convert+ds_write after the
//      finale; barrier at loop end. HBM latency hides under ~2000 cy compute.
// ---------------------------------------------------------------------------
__launch_bounds__(512, 2)
__global__ void uan_main(const float* __restrict__ Qg, const float* __restrict__ Kg,
                         const float* __restrict__ Vg, const _Float16* __restrict__ wt,
                         const float* __restrict__ Wl, const float* __restrict__ blv,
                         const float* __restrict__ Wsv, const float* __restrict__ bsv,
                         float* __restrict__ outg) {
  __shared__ __align__(16) _Float16 sF0[1536 * 8];   // 24576 B
  __shared__ __align__(16) _Float16 sF1[1536 * 8];   // 24576 B
  __shared__ __align__(16) _Float16 sVAf[256 * 8];   //  4096 B

  const int tid  = threadIdx.x;
  const int lane = tid & 63;
  const int w    = tid >> 6;        // wave 0..7 == head
  const int c16  = lane & 15;
  const int kg   = lane >> 4;

  // ---- held B-fragments (loaded once per block life) ----
  f16x8 bwp[24];   // proj: [p*8 + ks], head w
#pragma unroll
  for (int p = 0; p < 3; ++p)
#pragma unroll
    for (int ks = 0; ks < 8; ++ks)
      bwp[p * 8 + ks] = *(const f16x8*)(wt + p * 32768 +
                         (size_t)(((w * 8 + ks) * 64) + lane) * 8);
  f16x8 bo[8];     // W_o: [nt*4 + ks], tiles nto = 2w, 2w+1
#pragma unroll
  for (int nt = 0; nt < 2; ++nt)
#pragma unroll
    for (int ks = 0; ks < 4; ++ks)
      bo[nt * 4 + ks] = *(const f16x8*)(wt + 98304 +
                         (size_t)((((2 * w + nt) * 4 + ks) * 64) + lane) * 8);

  const float bl0 = blv[0], bl1 = blv[1], bs0 = bsv[0];
  // per-register softmax constants: hd = kg*4 + q
  float wl0q[4], wl1q[4], wsq[4];
#pragma unroll
  for (int q = 0; q < 4; ++q) {
    wl0q[q] = Wl[kg * 4 + q];
    wl1q[q] = Wl[16 + kg * 4 + q];
    wsq[q]  = Wsv[kg * 4 + q];
  }

  // staging: thread stages rows row0+c16's cols [w*32+kg*8, +8) of each plane
  const size_t soff  = (size_t)c16 * DIM + w * 32 + kg * 8;
  const size_t sfrag = (size_t)(w * 64 + lane) * 8;   // + p*4096 per plane

  float4 sa[3][2];
  auto issue_stage = [&](int t) {
    const size_t row0 = ((size_t)blockIdx.x * TPB + t) * BM;
#pragma unroll
    for (int p = 0; p < 3; ++p) {
      const float* base = (p == 0) ? Qg : ((p == 1) ? Kg : Vg);
      const float* src  = base + row0 * DIM + soff;
      sa[p][0] = *(const float4*)src;
      sa[p][1] = *(const float4*)(src + 4);
    }
  };
  auto write_stage = [&](_Float16* sFn) {
#pragma unroll
    for (int p = 0; p < 3; ++p) {
      f16x8 h;
      h[0] = (_Float16)sa[p][0].x; h[1] = (_Float16)sa[p][0].y;
      h[2] = (_Float16)sa[p][0].z; h[3] = (_Float16)sa[p][0].w;
      h[4] = (_Float16)sa[p][1].x; h[5] = (_Float16)sa[p][1].y;
      h[6] = (_Float16)sa[p][1].z; h[7] = (_Float16)sa[p][1].w;
      *(f16x8*)(sFn + p * 4096 + sfrag) = h;
    }
  };

  // prologue: stage tile 0
  issue_stage(0);
  write_stage(sF0);
  __syncthreads();

  for (int t = 0; t < TPB; ++t) {
    _Float16* sFc = (t & 1) ? sF1 : sF0;
    _Float16* sFn = (t & 1) ? sF0 : sF1;
    const bool doStage = (t + 1 < TPB);
    if (doStage) issue_stage(t + 1);     // loads in flight across this tile

    // ---- projections, swapped operands: accP holds P^T (row=c16, hd=kg*4+q) ----
    f32x4 accP[3] = {};
#pragma unroll
    for (int p = 0; p < 3; ++p)
#pragma unroll
      for (int ks = 0; ks < 8; ++ks) {
        const f16x8 af = *(const f16x8*)(sFc + (size_t)(((p * 8 + ks) * 64) + lane) * 8);
        accP[p] = __builtin_amdgcn_mfma_f32_16x16x32_f16(bwp[p * 8 + ks], af, accP[p], 0, 0, 0);
      }

    // ---- gated softmax: head-dim is register axis; reduce = 3 adds + 2 shfl ----
    float va[4];
    {
      float left[4], right[4];
      float pd0 = 0.f, pd1 = 0.f;
#pragma unroll
      for (int q = 0; q < 4; ++q) {
        const float qh = accP[0][q], kh = accP[1][q], vh = accP[2][q];
        left[q]  = kh * qh;
        right[q] = vh * qh;
        pd0 += left[q] * wl0q[q];
        pd1 += left[q] * wl1q[q];
      }
      pd0 += __shfl_xor(pd0, 16); pd0 += __shfl_xor(pd0, 32);
      pd1 += __shfl_xor(pd1, 16); pd1 += __shfl_xor(pd1, 32);
      const float m0 = 1.f / (1.f + __expf(-(pd0 + bl0)));
      const float m1 = 1.f / (1.f + __expf(-(pd1 + bl1)));
      const float mm = m0 * m1;
      float pnum = 0.f, pden = 0.f;
      float ev[4];
#pragma unroll
      for (int q = 0; q < 4; ++q) {
        ev[q] = __expf(left[q] * mm);    // |arg| <~ 40: f32-safe without max-sub
        pnum += ev[q] * wsq[q];
        pden += ev[q];
      }
      pnum += __shfl_xor(pnum, 16); pnum += __shfl_xor(pnum, 32);
      pden += __shfl_xor(pden, 16); pden += __shfl_xor(pden, 32);
      const float score = pnum / pden + bs0;
#pragma unroll
      for (int q = 0; q < 4; ++q) va[q] = score * right[q];
    }

    // ---- store V_att^T values into W_o A-fragment layout ----
    // V_att element (row=c16, k=w*16+kg*4+q); frag addr:
    // ((k>>5)*64 + ((k>>3)&3)*16 + row)*8 + (k&7)
#pragma unroll
    for (int q = 0; q < 4; ++q) {
      const int k = w * 16 + kg * 4 + q;
      sVAf[(size_t)((k >> 5) * 64 + ((k >> 3) & 3) * 16 + c16) * 8 + (k & 7)]
          = (_Float16)va[q];
    }
    __syncthreads();

    // ---- W_o: A = sVAf (LDS), B held; tiles nto = 2w, 2w+1 ----
    f32x4 accO[2] = {};
#pragma unroll
    for (int ks = 0; ks < 4; ++ks) {
      const f16x8 af = *(const f16x8*)(sVAf + (size_t)(ks * 64 + lane) * 8);
      accO[0] = __builtin_amdgcn_mfma_f32_16x16x32_f16(af, bo[ks],     accO[0], 0, 0, 0);
      accO[1] = __builtin_amdgcn_mfma_f32_16x16x32_f16(af, bo[4 + ks], accO[1], 0, 0, 0);
    }

    // ---- final: out = silu((V*Q) * V_att_out); lane cols = w*32 + c16*2 + {0,1} ----
    const size_t row0 = ((size_t)blockIdx.x * TPB + t) * BM;
#pragma unroll
    for (int q = 0; q < 4; ++q) {
      const size_t gb = (row0 + kg * 4 + q) * DIM + w * 32 + c16 * 2;
      float2 v2 = *(const float2*)(Vg + gb);
      float2 q2 = *(const float2*)(Qg + gb);
      const float att0 = v2.x * q2.x * accO[0][q];
      const float att1 = v2.y * q2.y * accO[1][q];
      float2 o;
      o.x = att0 / (1.f + __expf(-att0));
      o.y = att1 / (1.f + __expf(-att1));
      *(float2*)(outg + gb) = o;
    }

    // ---- write next tile's fragments; loop-end barrier covers all hazards ----
    if (doStage) {
      write_stage(sFn);
      __syncthreads();
    }
  }
}

// ---------------------------------------------------------------------------
extern "C" void kernel_launch(void* const* d_in, const int* in_sizes, int n_in,
                              void* d_out, int out_size, void* d_ws, size_t ws_size,
                              hipStream_t stream) {
  const float* Q  = (const float*)d_in[0];
  const float* K  = (const float*)d_in[1];
  const float* V  = (const float*)d_in[2];
  const float* Wq = (const float*)d_in[3];
  const float* Wk = (const float*)d_in[4];
  const float* Wv = (const float*)d_in[5];
  const float* Wo = (const float*)d_in[6];
  const float* Wl = (const float*)d_in[7];
  const float* bl = (const float*)d_in[8];
  const float* Ws = (const float*)d_in[9];
  const float* bs = (const float*)d_in[10];
  _Float16* wt = (_Float16*)d_ws;   // 131072 halves = 256 KB of scratch
  float* out = (float*)d_out;

  pack_w<<<512, 256, 0, stream>>>(Wq, Wk, Wv, Wo, wt);
  uan_main<<<NBLK, 512, 0, stream>>>(Q, K, V, wt, Wl, bl, Ws, bs, out);
}